// Round 6
// baseline (86.625 us; speedup 1.0000x reference)
//
#include <hip/hip_runtime.h>
#include <stdint.h>

// Problem constants
#define NTOT 8192   // B*(1+NPOS)
#define DD   128    // feature dim
#define BB   2048   // batch
#define NX   6144   // NPOS*B rows of x
// loss_neg subsample correction: log(4096/8191)
#define LOG_SUB_FRAC (-0.6930251f)
#define SQRT10 3.16227766017f
#define NBLK 2080   // 64*65/2 upper-tri tiles (scratch slots)
#define NCHK 1056   // sum over rows bi of ceil((64-bi)/2): 2-tile chunks
#define NPAN 64     // 128-row panels
#define FCUM(r) ((r) * 64 - ((r) * ((r) - 1)) / 2)

typedef __attribute__((ext_vector_type(4))) float floatx4;  // MFMA C/D
typedef __attribute__((ext_vector_type(4))) int   intx4;
typedef __attribute__((ext_vector_type(8))) int   intx8;    // 32 B fp8 frag

#define GLOBAL_AS(p) ((const __attribute__((address_space(1))) void*)(p))
#define LDS_AS(p)    ((__attribute__((address_space(3))) void*)(p))
// Write-through store / coherent-point load (agent scope, no RMW, no fence).
#define WT_STORE(p, v) __hip_atomic_store((p), (v), __ATOMIC_RELAXED, __HIP_MEMORY_SCOPE_AGENT)
#define CP_LOAD(p)     __hip_atomic_load((p), __ATOMIC_RELAXED, __HIP_MEMORY_SCOPE_AGENT)

// DPP add: s + permuted(s). Row = 16 lanes on CDNA.
template <int CTRL>
__device__ __forceinline__ float dpp_add(float s) {
  return s + __int_as_float(
      __builtin_amdgcn_update_dpp(0, __float_as_int(s), CTRL, 0xF, 0xF, true));
}
// Sum across a 16-lane row (result in all 16 lanes): xor1, xor2, ror4, ror8.
__device__ __forceinline__ float row16_sum(float s) {
  s = dpp_add<0xB1>(s);   // quad_perm [1,0,3,2]
  s = dpp_add<0x4E>(s);   // quad_perm [2,3,0,1]
  s = dpp_add<0x124>(s);  // row_ror:4
  s = dpp_add<0x128>(s);  // row_ror:8
  return s;
}

// K1: L2-normalize rows of z = [x ; x_pair], scale by sqrt(10) (folds 1/TEMP
// into the MFMA so sim accumulates 10*cos directly) -> fp8 e4m3 (OCP).
// Fused positive dots (pure f32, unscaled). One wave per row.
// Zero-inits the accumulators + both counters (stream-ordered flush at the
// K1->K2 boundary).
__global__ __launch_bounds__(256) void mp_norm(const float* __restrict__ x,
                                               const float* __restrict__ xp,
                                               uint8_t* __restrict__ znb8,
                                               float* __restrict__ pos,
                                               float* __restrict__ accs,
                                               uint32_t* __restrict__ cnts) {
  if (blockIdx.x == 0 && threadIdx.x == 0) {
    accs[0] = 0.f; accs[1] = 0.f; cnts[0] = 0u; cnts[1] = 0u;
  }

  const int row  = blockIdx.x * 4 + (threadIdx.x >> 6);
  const int lane = threadIdx.x & 63;
  const bool isx = row < NX;
  const float* src = isx ? (x + (size_t)row * DD) : (xp + (size_t)(row - NX) * DD);
  float2 v = ((const float2*)src)[lane];
  float ss = v.x * v.x + v.y * v.y;

  float ssp = 0.f, d = 0.f;
  if (isx) {
    const int b = row & (BB - 1);
    float2 p = ((const float2*)(xp + (size_t)b * DD))[lane];
    ssp = p.x * p.x + p.y * p.y;
    d = v.x * p.x + v.y * p.y;
  }
  // wave-wide sums (all lanes get result)
  ss  = row16_sum(ss);  ss  += __shfl_xor(ss, 16, 64);  ss  += __shfl_xor(ss, 32, 64);
  if (isx) {
    ssp = row16_sum(ssp); ssp += __shfl_xor(ssp, 16, 64); ssp += __shfl_xor(ssp, 32, 64);
    d   = row16_sum(d);   d   += __shfl_xor(d, 16, 64);   d   += __shfl_xor(d, 32, 64);
  }
  const float rn = rsqrtf(ss);           // pure normalizer (for pos)
  const float rns = rn * SQRT10;         // scaled for znb8
  const int pk = __builtin_amdgcn_cvt_pk_fp8_f32(v.x * rns, v.y * rns, 0, false);
  *(uint16_t*)(znb8 + (size_t)row * DD + lane * 2) = (uint16_t)(pk & 0xffff);
  if (isx && lane == 0) pos[row] = d * rn * rsqrtf(ssp);
}

// K2: upper-triangle 128x128 tiles of 10*sim = Zs*Zs^T via MX-scaled fp8 MFMA
// (mfma_scale_f32_16x16x128_f8f6f4, fmt=e4m3, unit scales 0x7F -> x1.0),
// 2-tile chunks per block (R4), LDS staging (R2 lesson), no fences (R1
// lesson), no RMW-atomic reduction (R3 lesson).
// R5 lesson: halving drains/staging was NEUTRAL -> K2 internals are not the
// critical path; remaining budget is launch/boundary overhead + the old K3's
// latency-bound gather (64 blocks, 64 serial 4B loads/thread).
// This round: K3 is FUSED as a distributed tail. scratch is written
// WRITE-THROUGH (atomic relaxed stores -> coherent point, no dirty L2, no
// RMW); each block vmcnt-drains then bumps a relaxed counter (R4-proven).
// The last 64 blocks each claim one 128-row panel, spin (bounded: they
// already bumped; <=63 stragglers always have free slots to dispatch) until
// all chunks are done, then gather with 256 threads (k-split x2, unroll 8),
// log+reduce, 2 scalar atomicAdds; the 64th tail block emits the scalar.
__global__ __launch_bounds__(256, 3) void mp_simexp(const uint8_t* __restrict__ znb8,
                                                    float* __restrict__ scratch,
                                                    const float* __restrict__ pos,
                                                    float* __restrict__ accs,
                                                    uint32_t* __restrict__ cnts,
                                                    float* __restrict__ out) {
  __shared__ uint8_t Abuf[128 * 128];
  __shared__ uint8_t Bbuf[2][128 * 128];
  __shared__ float comb[3 * 256];
  __shared__ int myord, lastf;

  // Chunk decode: block p -> row bi, first tile bj0 = bi + 2*(chunk idx).
  // Row bi has ceil((64-bi)/2) = (65-bi)>>1 chunks.
  int p = blockIdx.x, bi = 0, nch = 32;
  while (p >= nch) { p -= nch; ++bi; nch = (65 - bi) >> 1; }
  const int bj0 = bi + p * 2;
  const int nt = ((64 - bj0) >= 2) ? 2 : 1;     // tiles in this chunk
  const bool d0 = (bj0 == bi);                  // first tile is diagonal
  const int t0 = FCUM(bi) + (bj0 - bi);         // scratch slot of tile 0

  const int tid  = threadIdx.x;
  const int wave = tid >> 6, lane = tid & 63;
  const int lhi = lane >> 4, llo = lane & 15;
  const int wr = wave >> 1, wc = wave & 1;

  // Stage A and the non-diag B tiles: 16 B/lane, each wave-instr covers 8
  // rows (128 B/row); lane l -> row c*8+(l>>3), 16-B pair pq=(l&7)^(row&7)
  // (global source swizzled; LDS dest lane-contiguous). ONE drain for all.
  const uint8_t* gA = znb8 + (size_t)bi * 128 * DD;
  #pragma unroll
  for (int tc = 0; tc < 4; ++tc) {
    const int c = wave * 4 + tc;
    const int row = c * 8 + (lane >> 3);
    const int pq = (lane & 7) ^ (row & 7);
    const int roff = row * DD + pq * 16;
    __builtin_amdgcn_global_load_lds(GLOBAL_AS(gA + roff), LDS_AS(&Abuf[c * 1024]), 16, 0, 0);
    if (!d0)
      __builtin_amdgcn_global_load_lds(GLOBAL_AS(znb8 + (size_t)bj0 * 128 * DD + roff),
                                       LDS_AS(&Bbuf[0][c * 1024]), 16, 0, 0);
    if (nt == 2)
      __builtin_amdgcn_global_load_lds(GLOBAL_AS(znb8 + (size_t)(bj0 + 1) * 128 * DD + roff),
                                       LDS_AS(&Bbuf[1][c * 1024]), 16, 0, 0);
  }
  __syncthreads();

  // Row partials persist across both tiles (same A panel / same rows).
  float rowacc[4][4];
  #pragma unroll
  for (int r = 0; r < 4; ++r)
    #pragma unroll
    for (int j = 0; j < 4; ++j) rowacc[r][j] = 0.f;

  for (int s = 0; s < nt; ++s) {
    const bool diag = (s == 0) && d0;
    const uint8_t* Bs = diag ? Abuf : Bbuf[s];

    // Frag: lane(llo=row, lhi): 32 contiguous K bytes at lhi*32 = swizzled
    // 16-B pairs (2*lhi)^(row&7), (2*lhi+1)^(row&7). K-permutation
    // invariance: identical addressing for A/B frags cancels in Z*Z^T.
    intx8 bfrag[4];
    #pragma unroll
    for (int c = 0; c < 4; ++c) {
      const int row = wc * 64 + c * 16 + llo;
      const uint8_t* base = Bs + row * DD;
      intx4 lo = *(const intx4*)(base + (((2 * lhi)     ^ (row & 7)) << 4));
      intx4 hi = *(const intx4*)(base + (((2 * lhi + 1) ^ (row & 7)) << 4));
      bfrag[c] = intx8{lo.x, lo.y, lo.z, lo.w, hi.x, hi.y, hi.z, hi.w};
    }
    floatx4 acc[4][4] = {};
    #pragma unroll
    for (int r = 0; r < 4; ++r) {
      const int row = wr * 64 + r * 16 + llo;
      const uint8_t* base = Abuf + row * DD;
      intx4 lo = *(const intx4*)(base + (((2 * lhi)     ^ (row & 7)) << 4));
      intx4 hi = *(const intx4*)(base + (((2 * lhi + 1) ^ (row & 7)) << 4));
      intx8 afrag = intx8{lo.x, lo.y, lo.z, lo.w, hi.x, hi.y, hi.z, hi.w};
      #pragma unroll
      for (int c = 0; c < 4; ++c)
        acc[r][c] = __builtin_amdgcn_mfma_scale_f32_16x16x128_f8f6f4(
            afrag, bfrag[c], acc[r][c], 0, 0, 0, 0x7F7F7F7F, 0, 0x7F7F7F7F);
    }

    // e = exp(acc) (acc is already 10*cos); diag masked (uniform branch).
    // C/D layout: col = lane&15, row = (lane>>4)*4 + reg.
    float colacc[4] = {0.f, 0.f, 0.f, 0.f};
    if (diag) {
      #pragma unroll
      for (int r = 0; r < 4; ++r) {
        #pragma unroll
        for (int c = 0; c < 4; ++c) {
          const int col = wc * 64 + c * 16 + llo;
          #pragma unroll
          for (int j = 0; j < 4; ++j) {
            const int row = wr * 64 + r * 16 + lhi * 4 + j;
            float e = __expf(acc[r][c][j]);
            if (row == col) e = 0.f;
            rowacc[r][j] += e;
            colacc[c] += e;
          }
        }
      }
    } else {
      #pragma unroll
      for (int r = 0; r < 4; ++r) {
        #pragma unroll
        for (int c = 0; c < 4; ++c) {
          #pragma unroll
          for (int j = 0; j < 4; ++j) {
            float e = __expf(acc[r][c][j]);
            rowacc[r][j] += e;
            colacc[c] += e;
          }
        }
      }
    }
    // Col partials for this tile -> comb[256*(1+s)] (diag tile's col-half
    // is never read by the gather; writing it is harmless).
    #pragma unroll
    for (int c = 0; c < 4; ++c) {
      float sc = colacc[c];
      sc += __shfl_xor(sc, 16, 64);
      sc += __shfl_xor(sc, 32, 64);          // full col sum over wave's 64 rows
      if (lhi == 0) comb[256 * (1 + s) + wr * 128 + wc * 64 + c * 16 + llo] = sc;
    }
  }

  // Row partials (whole chunk) -> comb[0..256).
  #pragma unroll
  for (int r = 0; r < 4; ++r) {
    #pragma unroll
    for (int j = 0; j < 4; ++j) {
      float s = row16_sum(rowacc[r][j]);     // row sum over wave's 64 cols (x nt tiles)
      if (llo == j) comb[wc * 128 + wr * 64 + r * 16 + lhi * 4 + j] = s;
    }
  }
  __syncthreads();

  // Coalesced WRITE-THROUGH stores (visible at coherent point once acked).
  // Row-half of t0 = chunk row partials; t1 row-half = 0 (gather reads all
  // 64 slots uniformly). Col-halves per tile.
  if (tid < 128) {
    WT_STORE(&scratch[(size_t)t0 * 256 + tid], comb[tid] + comb[128 + tid]);
    if (nt == 2) WT_STORE(&scratch[(size_t)(t0 + 1) * 256 + tid], 0.f);
  } else {
    const int i = tid - 128;
    WT_STORE(&scratch[(size_t)t0 * 256 + 128 + i], comb[256 + i] + comb[256 + 128 + i]);
    if (nt == 2)
      WT_STORE(&scratch[(size_t)(t0 + 1) * 256 + 128 + i], comb[512 + i] + comb[512 + 128 + i]);
  }

  // ---- distributed tail: last 64 blocks each reduce one panel ----
  asm volatile("s_waitcnt vmcnt(0)" ::: "memory");  // this wave's WT stores acked
  __syncthreads();                                   // all 4 waves drained
  if (tid == 0)
    myord = (int)__hip_atomic_fetch_add(&cnts[0], 1u, __ATOMIC_RELAXED,
                                        __HIP_MEMORY_SCOPE_AGENT);
  __syncthreads();
  if (myord < NCHK - NPAN) return;          // not a tail block
  const int P = myord - (NCHK - NPAN);      // claimed panel

  if (tid == 0) {                           // bounded spin: all blocks bump
    while (__hip_atomic_load(&cnts[0], __ATOMIC_RELAXED,
                             __HIP_MEMORY_SCOPE_AGENT) < NCHK)
      __builtin_amdgcn_s_sleep(2);
  }
  __syncthreads();

  // Gather panel P: row z = P*128+idx sums 64 partials, k-split over h.
  //   k < nrow: row-half of tile (P, P+k) at slot FCUM(P)+k
  //   else    : col-half of tile (b2, P), b2=k-nrow, at slot FCUM(b2)+(P-b2)
  const int idx = tid & 127, h = tid >> 7;
  const int nrow = NPAN - P;
  const int base = FCUM(P);
  float s = 0.f;
  #pragma unroll 8
  for (int kk = 0; kk < 32; ++kk) {
    const int k = h * 32 + kk;
    int off;
    if (k < nrow) {
      off = (base + k) * 256 + idx;
    } else {
      const int b2 = k - nrow;
      off = (FCUM(b2) + (P - b2)) * 256 + 128 + idx;
    }
    s += CP_LOAD(&scratch[off]);
  }
  comb[h * 128 + idx] = s;
  __syncthreads();

  float l = 0.f, pp = 0.f;
  if (tid < 128) {
    l = logf(comb[idx] + comb[128 + idx]);
    pp = (P < 48) ? pos[P * 128 + idx] : 0.f;   // panels 0..47 are x-rows
  }
  #pragma unroll
  for (int m = 1; m < 64; m <<= 1) {
    l += __shfl_xor(l, m, 64);
    pp += __shfl_xor(pp, m, 64);
  }
  __shared__ float rl2[4], rp2[4];
  if ((tid & 63) == 0) { rl2[tid >> 6] = l; rp2[tid >> 6] = pp; }
  __syncthreads();
  if (tid == 0) {
    atomicAdd(&accs[0], rl2[0] + rl2[1]);     // 64 tail blocks x 2 RMWs: trivial
    atomicAdd(&accs[1], rp2[0] + rp2[1]);
  }
  asm volatile("s_waitcnt vmcnt(0)" ::: "memory");
  __syncthreads();
  if (tid == 0) {
    uint32_t o2 = __hip_atomic_fetch_add(&cnts[1], 1u, __ATOMIC_RELAXED,
                                         __HIP_MEMORY_SCOPE_AGENT);
    lastf = (o2 == NPAN - 1);
  }
  __syncthreads();
  if (lastf && tid == 0) {
    const float S  = CP_LOAD(&accs[0]);
    const float Pp = CP_LOAD(&accs[1]);
    const float loss_neg = S / (float)NTOT + LOG_SUB_FRAC;
    const float loss_pos = Pp * (10.0f / (float)NX);  // WEIGHT*(1/TEMP)/(B*NPOS)
    out[0] = loss_neg - loss_pos;
  }
}

extern "C" void kernel_launch(void* const* d_in, const int* in_sizes, int n_in,
                              void* d_out, int out_size, void* d_ws, size_t ws_size,
                              hipStream_t stream) {
  const float* x  = (const float*)d_in[0];   // [6144, 128] f32
  const float* xp = (const float*)d_in[1];   // [2048, 128] f32
  float* out = (float*)d_out;                // scalar f32

  char* ws = (char*)d_ws;
  uint8_t* znb8  = (uint8_t*)ws;                                   // 1 MB
  float* pos     = (float*)(ws + (1u << 20));                      // 24 KB (pad 32K)
  float* scratch = (float*)(ws + (1u << 20) + (32u << 10));        // 2080*1KB
  float* accs    = (float*)(ws + (1u << 20) + (32u << 10) + NBLK * 1024u);
  uint32_t* cnts = (uint32_t*)(ws + (1u << 20) + (32u << 10) + NBLK * 1024u + 8u);

  mp_norm<<<NTOT / 4, 256, 0, stream>>>(x, xp, znb8, pos, accs, cnts);
  mp_simexp<<<NCHK, 256, 0, stream>>>(znb8, scratch, pos, accs, cnts, out);
}

// Round 7
// 77.963 us; speedup vs baseline: 1.1111x; 1.1111x over previous
//
#include <hip/hip_runtime.h>
#include <stdint.h>

// Problem constants
#define NTOT 8192   // B*(1+NPOS)
#define DD   128    // feature dim
#define BB   2048   // batch
#define NX   6144   // NPOS*B rows of x
// loss_neg subsample correction: log(4096/8191)
#define LOG_SUB_FRAC (-0.6930251f)
#define SQRT10 3.16227766017f
#define NBLK 2080   // 64*65/2 upper-tri tiles (scratch slots)
#define NCHK 1056   // sum over rows bi of ceil((64-bi)/2): 2-tile chunks
#define NPAN 64     // 128-row panels
#define FCUM(r) ((r) * 64 - ((r) * ((r) - 1)) / 2)

typedef __attribute__((ext_vector_type(4))) float floatx4;  // MFMA C/D
typedef __attribute__((ext_vector_type(4))) int   intx4;
typedef __attribute__((ext_vector_type(8))) int   intx8;    // 32 B fp8 frag

#define GLOBAL_AS(p) ((const __attribute__((address_space(1))) void*)(p))
#define LDS_AS(p)    ((__attribute__((address_space(3))) void*)(p))

// DPP add: s + permuted(s). Row = 16 lanes on CDNA.
template <int CTRL>
__device__ __forceinline__ float dpp_add(float s) {
  return s + __int_as_float(
      __builtin_amdgcn_update_dpp(0, __float_as_int(s), CTRL, 0xF, 0xF, true));
}
// Sum across a 16-lane row (result in all 16 lanes): xor1, xor2, ror4, ror8.
__device__ __forceinline__ float row16_sum(float s) {
  s = dpp_add<0xB1>(s);   // quad_perm [1,0,3,2]
  s = dpp_add<0x4E>(s);   // quad_perm [2,3,0,1]
  s = dpp_add<0x124>(s);  // row_ror:4
  s = dpp_add<0x128>(s);  // row_ror:8
  return s;
}

// K1: L2-normalize rows of z = [x ; x_pair], scale by sqrt(10) (folds 1/TEMP
// into the MFMA so sim accumulates 10*cos directly) -> fp8 e4m3 (OCP).
// Fused positive dots (pure f32, unscaled). One wave per row.
// Zero-inits the accumulators + counter (stream-ordered flush at boundary).
__global__ __launch_bounds__(256) void mp_norm(const float* __restrict__ x,
                                               const float* __restrict__ xp,
                                               uint8_t* __restrict__ znb8,
                                               float* __restrict__ pos,
                                               float* __restrict__ accs,
                                               uint32_t* __restrict__ cnt) {
  if (blockIdx.x == 0 && threadIdx.x == 0) {
    accs[0] = 0.f; accs[1] = 0.f; *cnt = 0u;
  }

  const int row  = blockIdx.x * 4 + (threadIdx.x >> 6);
  const int lane = threadIdx.x & 63;
  const bool isx = row < NX;
  const float* src = isx ? (x + (size_t)row * DD) : (xp + (size_t)(row - NX) * DD);
  float2 v = ((const float2*)src)[lane];
  float ss = v.x * v.x + v.y * v.y;

  float ssp = 0.f, d = 0.f;
  if (isx) {
    const int b = row & (BB - 1);
    float2 p = ((const float2*)(xp + (size_t)b * DD))[lane];
    ssp = p.x * p.x + p.y * p.y;
    d = v.x * p.x + v.y * p.y;
  }
  // wave-wide sums (all lanes get result)
  ss  = row16_sum(ss);  ss  += __shfl_xor(ss, 16, 64);  ss  += __shfl_xor(ss, 32, 64);
  if (isx) {
    ssp = row16_sum(ssp); ssp += __shfl_xor(ssp, 16, 64); ssp += __shfl_xor(ssp, 32, 64);
    d   = row16_sum(d);   d   += __shfl_xor(d, 16, 64);   d   += __shfl_xor(d, 32, 64);
  }
  const float rn = rsqrtf(ss);           // pure normalizer (for pos)
  const float rns = rn * SQRT10;         // scaled for znb8
  const int pk = __builtin_amdgcn_cvt_pk_fp8_f32(v.x * rns, v.y * rns, 0, false);
  *(uint16_t*)(znb8 + (size_t)row * DD + lane * 2) = (uint16_t)(pk & 0xffff);
  if (isx && lane == 0) pos[row] = d * rn * rsqrtf(ssp);
}

// K2: upper-triangle 128x128 tiles of 10*sim = Zs*Zs^T via MX-scaled fp8 MFMA
// (mfma_scale_f32_16x16x128_f8f6f4, fmt=e4m3, unit scales 0x7F -> x1.0),
// 2-tile chunks per block (R4). Ledger: LDS staging kept (R2: destaging
// +10us); no RMW-atomic reduction (R3: ~1M atomics = the 30us storm); no
// fences (R1: threadfence = 180us); no cross-block fusion (R1/R6: fusion
// lost to a clean kernel boundary twice). Plain cached stores to scratch;
// coherence via the K2->K3 stream boundary.
// R7 edit: tile-1 row-half zero store removed (K3 now skips those slots).
__global__ __launch_bounds__(256, 3) void mp_simexp(const uint8_t* __restrict__ znb8,
                                                    float* __restrict__ scratch) {
  __shared__ uint8_t Abuf[128 * 128];
  __shared__ uint8_t Bbuf[2][128 * 128];
  __shared__ float comb[3 * 256];   // [0,256)=row halves, [256,512)=col t0, [512,768)=col t1

  // Chunk decode: block p -> row bi, first tile bj0 = bi + 2*(chunk idx).
  // Row bi has ceil((64-bi)/2) = (65-bi)>>1 chunks.
  int p = blockIdx.x, bi = 0, nch = 32;
  while (p >= nch) { p -= nch; ++bi; nch = (65 - bi) >> 1; }
  const int bj0 = bi + p * 2;
  const int nt = ((64 - bj0) >= 2) ? 2 : 1;     // tiles in this chunk
  const bool d0 = (bj0 == bi);                  // first tile is diagonal
  const int t0 = FCUM(bi) + (bj0 - bi);         // scratch slot of tile 0

  const int tid  = threadIdx.x;
  const int wave = tid >> 6, lane = tid & 63;
  const int lhi = lane >> 4, llo = lane & 15;
  const int wr = wave >> 1, wc = wave & 1;

  // Stage A and the non-diag B tiles: 16 B/lane, each wave-instr covers 8
  // rows (128 B/row); lane l -> row c*8+(l>>3), 16-B pair pq=(l&7)^(row&7)
  // (global source swizzled; LDS dest lane-contiguous). ONE drain for all.
  const uint8_t* gA = znb8 + (size_t)bi * 128 * DD;
  #pragma unroll
  for (int tc = 0; tc < 4; ++tc) {
    const int c = wave * 4 + tc;
    const int row = c * 8 + (lane >> 3);
    const int pq = (lane & 7) ^ (row & 7);
    const int roff = row * DD + pq * 16;
    __builtin_amdgcn_global_load_lds(GLOBAL_AS(gA + roff), LDS_AS(&Abuf[c * 1024]), 16, 0, 0);
    if (!d0)
      __builtin_amdgcn_global_load_lds(GLOBAL_AS(znb8 + (size_t)bj0 * 128 * DD + roff),
                                       LDS_AS(&Bbuf[0][c * 1024]), 16, 0, 0);
    if (nt == 2)
      __builtin_amdgcn_global_load_lds(GLOBAL_AS(znb8 + (size_t)(bj0 + 1) * 128 * DD + roff),
                                       LDS_AS(&Bbuf[1][c * 1024]), 16, 0, 0);
  }
  __syncthreads();

  // Row partials persist across both tiles (same A panel / same rows).
  float rowacc[4][4];
  #pragma unroll
  for (int r = 0; r < 4; ++r)
    #pragma unroll
    for (int j = 0; j < 4; ++j) rowacc[r][j] = 0.f;

  for (int s = 0; s < nt; ++s) {
    const bool diag = (s == 0) && d0;
    const uint8_t* Bs = diag ? Abuf : Bbuf[s];

    // Frag: lane(llo=row, lhi): 32 contiguous K bytes at lhi*32 = swizzled
    // 16-B pairs (2*lhi)^(row&7), (2*lhi+1)^(row&7). K-permutation
    // invariance: identical addressing for A/B frags cancels in Z*Z^T.
    intx8 bfrag[4];
    #pragma unroll
    for (int c = 0; c < 4; ++c) {
      const int row = wc * 64 + c * 16 + llo;
      const uint8_t* base = Bs + row * DD;
      intx4 lo = *(const intx4*)(base + (((2 * lhi)     ^ (row & 7)) << 4));
      intx4 hi = *(const intx4*)(base + (((2 * lhi + 1) ^ (row & 7)) << 4));
      bfrag[c] = intx8{lo.x, lo.y, lo.z, lo.w, hi.x, hi.y, hi.z, hi.w};
    }
    floatx4 acc[4][4] = {};
    #pragma unroll
    for (int r = 0; r < 4; ++r) {
      const int row = wr * 64 + r * 16 + llo;
      const uint8_t* base = Abuf + row * DD;
      intx4 lo = *(const intx4*)(base + (((2 * lhi)     ^ (row & 7)) << 4));
      intx4 hi = *(const intx4*)(base + (((2 * lhi + 1) ^ (row & 7)) << 4));
      intx8 afrag = intx8{lo.x, lo.y, lo.z, lo.w, hi.x, hi.y, hi.z, hi.w};
      #pragma unroll
      for (int c = 0; c < 4; ++c)
        acc[r][c] = __builtin_amdgcn_mfma_scale_f32_16x16x128_f8f6f4(
            afrag, bfrag[c], acc[r][c], 0, 0, 0, 0x7F7F7F7F, 0, 0x7F7F7F7F);
    }

    // e = exp(acc) (acc is already 10*cos); diag masked (uniform branch).
    // C/D layout: col = lane&15, row = (lane>>4)*4 + reg.
    float colacc[4] = {0.f, 0.f, 0.f, 0.f};
    if (diag) {
      #pragma unroll
      for (int r = 0; r < 4; ++r) {
        #pragma unroll
        for (int c = 0; c < 4; ++c) {
          const int col = wc * 64 + c * 16 + llo;
          #pragma unroll
          for (int j = 0; j < 4; ++j) {
            const int row = wr * 64 + r * 16 + lhi * 4 + j;
            float e = __expf(acc[r][c][j]);
            if (row == col) e = 0.f;
            rowacc[r][j] += e;
            colacc[c] += e;
          }
        }
      }
    } else {
      #pragma unroll
      for (int r = 0; r < 4; ++r) {
        #pragma unroll
        for (int c = 0; c < 4; ++c) {
          #pragma unroll
          for (int j = 0; j < 4; ++j) {
            float e = __expf(acc[r][c][j]);
            rowacc[r][j] += e;
            colacc[c] += e;
          }
        }
      }
    }
    // Col partials for this tile -> comb[256*(1+s)] (diag tile's col-half
    // is never read by K3; writing it is harmless).
    #pragma unroll
    for (int c = 0; c < 4; ++c) {
      float sc = colacc[c];
      sc += __shfl_xor(sc, 16, 64);
      sc += __shfl_xor(sc, 32, 64);          // full col sum over wave's 64 rows
      if (lhi == 0) comb[256 * (1 + s) + wr * 128 + wc * 64 + c * 16 + llo] = sc;
    }
  }

  // Row partials (whole chunk) -> comb[0..256).
  #pragma unroll
  for (int r = 0; r < 4; ++r) {
    #pragma unroll
    for (int j = 0; j < 4; ++j) {
      float s = row16_sum(rowacc[r][j]);     // row sum over wave's 64 cols (x nt tiles)
      if (llo == j) comb[wc * 128 + wr * 64 + r * 16 + lhi * 4 + j] = s;
    }
  }
  __syncthreads();

  // Coalesced stores. Row-half of t0 = chunk row partials (K3 reads row
  // partials ONLY at chunk-start slots now). Col-halves per tile.
  if (tid < 128) {
    scratch[(size_t)t0 * 256 + tid] = comb[tid] + comb[128 + tid];
  } else {
    const int i = tid - 128;
    scratch[(size_t)t0 * 256 + 128 + i] = comb[256 + i] + comb[256 + 128 + i];
    if (nt == 2)
      scratch[(size_t)(t0 + 1) * 256 + 128 + i] = comb[512 + i] + comb[512 + 128 + i];
  }
}

// K3: gather-reduce + fused tail. One block per 128-row panel P (64 blocks,
// 256 threads, k-split x2 over the partial list). Row z = P*128+idx sums:
//   chunk row-halves of row P:  slots FCUM(P)+2m, m=0..ceil((64-P)/2)-1
//   col-halves (bi,P), bi<P:    slots FCUM(bi)+(P-bi)
// (R7: compacted list — zero t1 row-halves no longer read; 256-thread
// k-split halves per-thread serial load count of the latency-bound gather.)
// Then log, block-reduce, 2 atomicAdds; last block (relaxed counter, no
// fences — 64 blocks, negligible) emits the final scalar.
__global__ __launch_bounds__(256) void mp_reduce(const float* __restrict__ scratch,
                                                 const float* __restrict__ pos,
                                                 float* __restrict__ accs,
                                                 uint32_t* __restrict__ cnt,
                                                 float* __restrict__ out) {
  const int P = blockIdx.x;
  const int tid = threadIdx.x;
  const int idx = tid & 127, h = tid >> 7;       // h in {0,1}
  const int nr2 = (NPAN - P + 1) >> 1;           // chunks in triangle row P
  const int M = nr2 + P;                         // partials feeding this panel
  const int base = FCUM(P);

  float s = 0.f;
  #pragma unroll 4
  for (int k = h; k < M; k += 2) {
    int off;
    if (k < nr2) {
      off = (base + 2 * k) * 256 + idx;                    // row-half, chunk m=k
    } else {
      const int b2 = k - nr2;                              // bi in [0,P)
      off = (FCUM(b2) + (P - b2)) * 256 + 128 + idx;       // col-half (b2,P)
    }
    s += scratch[off];
  }
  __shared__ float part[256];
  part[tid] = s;
  __syncthreads();

  float l = 0.f, pp = 0.f;
  if (tid < 128) {
    l = logf(part[idx] + part[128 + idx]);
    pp = (P < 48) ? pos[P * 128 + idx] : 0.f;    // panels 0..47 are x-rows
  }
  #pragma unroll
  for (int m = 1; m < 64; m <<= 1) {
    l += __shfl_xor(l, m, 64);
    pp += __shfl_xor(pp, m, 64);
  }
  __shared__ float rl2[4], rp2[4];
  __shared__ int lastflag;
  if ((tid & 63) == 0) { rl2[tid >> 6] = l; rp2[tid >> 6] = pp; }
  __syncthreads();
  if (tid == 0) {
    atomicAdd(&accs[0], rl2[0] + rl2[1] + rl2[2] + rl2[3]);
    atomicAdd(&accs[1], rp2[0] + rp2[1] + rp2[2] + rp2[3]);
  }
  asm volatile("s_waitcnt vmcnt(0)" ::: "memory");  // this wave's atomics acked
  __syncthreads();
  if (tid == 0) {
    uint32_t old = __hip_atomic_fetch_add(cnt, 1u, __ATOMIC_RELAXED,
                                          __HIP_MEMORY_SCOPE_AGENT);
    lastflag = (old == NPAN - 1);
  }
  __syncthreads();
  if (lastflag && tid == 0) {
    float S  = __hip_atomic_load(&accs[0], __ATOMIC_RELAXED, __HIP_MEMORY_SCOPE_AGENT);
    float Pp = __hip_atomic_load(&accs[1], __ATOMIC_RELAXED, __HIP_MEMORY_SCOPE_AGENT);
    const float loss_neg = S / (float)NTOT + LOG_SUB_FRAC;
    const float loss_pos = Pp * (10.0f / (float)NX);  // WEIGHT*(1/TEMP)/(B*NPOS)
    out[0] = loss_neg - loss_pos;
  }
}

extern "C" void kernel_launch(void* const* d_in, const int* in_sizes, int n_in,
                              void* d_out, int out_size, void* d_ws, size_t ws_size,
                              hipStream_t stream) {
  const float* x  = (const float*)d_in[0];   // [6144, 128] f32
  const float* xp = (const float*)d_in[1];   // [2048, 128] f32
  float* out = (float*)d_out;                // scalar f32

  char* ws = (char*)d_ws;
  uint8_t* znb8  = (uint8_t*)ws;                                   // 1 MB
  float* pos     = (float*)(ws + (1u << 20));                      // 24 KB (pad 32K)
  float* scratch = (float*)(ws + (1u << 20) + (32u << 10));        // 2080*1KB
  float* accs    = (float*)(ws + (1u << 20) + (32u << 10) + NBLK * 1024u);
  uint32_t* cnt  = (uint32_t*)(ws + (1u << 20) + (32u << 10) + NBLK * 1024u + 8u);

  mp_norm<<<NTOT / 4, 256, 0, stream>>>(x, xp, znb8, pos, accs, cnt);
  mp_simexp<<<NCHK, 256, 0, stream>>>(znb8, scratch);
  mp_reduce<<<NPAN, 256, 0, stream>>>(scratch, pos, accs, cnt, out);
}

// Round 8
// 76.151 us; speedup vs baseline: 1.1375x; 1.0238x over previous
//
#include <hip/hip_runtime.h>
#include <stdint.h>

// Problem constants
#define NTOT 8192   // B*(1+NPOS)
#define DD   128    // feature dim
#define BB   2048   // batch
#define NX   6144   // NPOS*B rows of x
// loss_neg subsample correction: log(4096/8191)
#define LOG_SUB_FRAC (-0.6930251f)
#define SQRT10 3.16227766017f
#define NBLK 2080   // 64*65/2 upper-tri tiles (scratch slots)
#define NCHK 1056   // sum over rows bi of ceil((64-bi)/2): 2-tile chunks
#define NPAN 64     // 128-row panels
#define FCUM(r) ((r) * 64 - ((r) * ((r) - 1)) / 2)

typedef __attribute__((ext_vector_type(4))) float floatx4;  // MFMA C/D
typedef __attribute__((ext_vector_type(4))) int   intx4;
typedef __attribute__((ext_vector_type(8))) int   intx8;    // 32 B fp8 frag

#define GLOBAL_AS(p) ((const __attribute__((address_space(1))) void*)(p))
#define LDS_AS(p)    ((__attribute__((address_space(3))) void*)(p))

// DPP add: s + permuted(s). Row = 16 lanes on CDNA.
template <int CTRL>
__device__ __forceinline__ float dpp_add(float s) {
  return s + __int_as_float(
      __builtin_amdgcn_update_dpp(0, __float_as_int(s), CTRL, 0xF, 0xF, true));
}
// Sum across a 16-lane row (result in all 16 lanes): xor1, xor2, ror4, ror8.
__device__ __forceinline__ float row16_sum(float s) {
  s = dpp_add<0xB1>(s);   // quad_perm [1,0,3,2]
  s = dpp_add<0x4E>(s);   // quad_perm [2,3,0,1]
  s = dpp_add<0x124>(s);  // row_ror:4
  s = dpp_add<0x128>(s);  // row_ror:8
  return s;
}

// K1: L2-normalize rows of z = [x ; x_pair], scale by sqrt(10) (folds 1/TEMP
// into the MFMA so sim accumulates 10*cos directly) -> fp8 e4m3 (OCP).
// Fused positive dots (pure f32, unscaled).
// R8: float4 loads (16 B/lane, G13 sweet spot) -> 2 rows per wave (one per
// 32-lane half), grid 2048 -> 1024 blocks. NX % 8 == 0 so isx is uniform
// per block. Zero-inits accumulators + counter (stream-ordered flush).
__global__ __launch_bounds__(256) void mp_norm(const float* __restrict__ x,
                                               const float* __restrict__ xp,
                                               uint8_t* __restrict__ znb8,
                                               float* __restrict__ pos,
                                               float* __restrict__ accs,
                                               uint32_t* __restrict__ cnt) {
  if (blockIdx.x == 0 && threadIdx.x == 0) {
    accs[0] = 0.f; accs[1] = 0.f; *cnt = 0u;
  }

  const int half = threadIdx.x >> 5;       // 0..7: half-wave owns one row
  const int i    = threadIdx.x & 31;       // float4 index within the row
  const int row  = blockIdx.x * 8 + half;
  const bool isx = row < NX;
  const float4* src = (const float4*)(isx ? x + (size_t)row * DD
                                          : xp + (size_t)(row - NX) * DD);
  float4 v = src[i];
  float ss = v.x * v.x + v.y * v.y + v.z * v.z + v.w * v.w;

  float ssp = 0.f, d = 0.f;
  if (isx) {
    const int b = row & (BB - 1);
    float4 p = ((const float4*)(xp + (size_t)b * DD))[i];
    ssp = p.x * p.x + p.y * p.y + p.z * p.z + p.w * p.w;
    d   = v.x * p.x + v.y * p.y + v.z * p.z + v.w * p.w;
  }
  // 32-lane sums (row16 tree + xor16 stays within each 32-lane half)
  ss  = row16_sum(ss);  ss  += __shfl_xor(ss, 16, 64);
  if (isx) {
    ssp = row16_sum(ssp); ssp += __shfl_xor(ssp, 16, 64);
    d   = row16_sum(d);   d   += __shfl_xor(d, 16, 64);
  }
  const float rn = rsqrtf(ss);           // pure normalizer (for pos)
  const float rns = rn * SQRT10;         // scaled for znb8
  const int pk0 = __builtin_amdgcn_cvt_pk_fp8_f32(v.x * rns, v.y * rns, 0, false);
  const int pk1 = __builtin_amdgcn_cvt_pk_fp8_f32(v.z * rns, v.w * rns, 0, false);
  const uint32_t word = (uint32_t)(pk0 & 0xffff) | ((uint32_t)(pk1 & 0xffff) << 16);
  *(uint32_t*)(znb8 + (size_t)row * DD + i * 4) = word;   // bytes e0..e3, coalesced
  if (isx && i == 0) pos[row] = d * rn * rsqrtf(ssp);
}

// K2: upper-triangle 128x128 tiles of 10*sim = Zs*Zs^T via MX-scaled fp8 MFMA
// (mfma_scale_f32_16x16x128_f8f6f4, fmt=e4m3, unit scales 0x7F -> x1.0),
// 2-tile chunks per block (R4). Ledger: LDS staging kept (R2: destaging
// +10us); no RMW-atomic reduction (R3: ~1M atomics = the 30us storm); no
// fences (R1: threadfence = 180us); no cross-block fusion (R1/R6: fusion
// lost to a clean kernel boundary twice); drain/staging micro-tuning neutral
// (R5). Plain cached stores to scratch; coherence via the K2->K3 boundary.
// R8: bijective XCD swizzle (1056 = 8*132): consecutive chunks of a triangle
// row (sharing the A panel) land on the same XCD for L2 panel reuse.
__global__ __launch_bounds__(256, 3) void mp_simexp(const uint8_t* __restrict__ znb8,
                                                    float* __restrict__ scratch) {
  __shared__ uint8_t Abuf[128 * 128];
  __shared__ uint8_t Bbuf[2][128 * 128];
  __shared__ float comb[3 * 256];   // [0,256)=row halves, [256,512)=col t0, [512,768)=col t1

  // XCD swizzle (bijective: 1056 % 8 == 0), then chunk decode:
  // block p -> row bi, first tile bj0 = bi + 2*(chunk idx).
  // Row bi has ceil((64-bi)/2) = (65-bi)>>1 chunks.
  int p = (blockIdx.x & 7) * 132 + (blockIdx.x >> 3);
  int bi = 0, nch = 32;
  while (p >= nch) { p -= nch; ++bi; nch = (65 - bi) >> 1; }
  const int bj0 = bi + p * 2;
  const int nt = ((64 - bj0) >= 2) ? 2 : 1;     // tiles in this chunk
  const bool d0 = (bj0 == bi);                  // first tile is diagonal
  const int t0 = FCUM(bi) + (bj0 - bi);         // scratch slot of tile 0

  const int tid  = threadIdx.x;
  const int wave = tid >> 6, lane = tid & 63;
  const int lhi = lane >> 4, llo = lane & 15;
  const int wr = wave >> 1, wc = wave & 1;

  // Stage A and the non-diag B tiles: 16 B/lane, each wave-instr covers 8
  // rows (128 B/row); lane l -> row c*8+(l>>3), 16-B pair pq=(l&7)^(row&7)
  // (global source swizzled; LDS dest lane-contiguous). ONE drain for all.
  const uint8_t* gA = znb8 + (size_t)bi * 128 * DD;
  #pragma unroll
  for (int tc = 0; tc < 4; ++tc) {
    const int c = wave * 4 + tc;
    const int row = c * 8 + (lane >> 3);
    const int pq = (lane & 7) ^ (row & 7);
    const int roff = row * DD + pq * 16;
    __builtin_amdgcn_global_load_lds(GLOBAL_AS(gA + roff), LDS_AS(&Abuf[c * 1024]), 16, 0, 0);
    if (!d0)
      __builtin_amdgcn_global_load_lds(GLOBAL_AS(znb8 + (size_t)bj0 * 128 * DD + roff),
                                       LDS_AS(&Bbuf[0][c * 1024]), 16, 0, 0);
    if (nt == 2)
      __builtin_amdgcn_global_load_lds(GLOBAL_AS(znb8 + (size_t)(bj0 + 1) * 128 * DD + roff),
                                       LDS_AS(&Bbuf[1][c * 1024]), 16, 0, 0);
  }
  __syncthreads();

  // Row partials persist across both tiles (same A panel / same rows).
  float rowacc[4][4];
  #pragma unroll
  for (int r = 0; r < 4; ++r)
    #pragma unroll
    for (int j = 0; j < 4; ++j) rowacc[r][j] = 0.f;

  for (int s = 0; s < nt; ++s) {
    const bool diag = (s == 0) && d0;
    const uint8_t* Bs = diag ? Abuf : Bbuf[s];

    // Frag: lane(llo=row, lhi): 32 contiguous K bytes at lhi*32 = swizzled
    // 16-B pairs (2*lhi)^(row&7), (2*lhi+1)^(row&7). K-permutation
    // invariance: identical addressing for A/B frags cancels in Z*Z^T.
    intx8 bfrag[4];
    #pragma unroll
    for (int c = 0; c < 4; ++c) {
      const int row = wc * 64 + c * 16 + llo;
      const uint8_t* base = Bs + row * DD;
      intx4 lo = *(const intx4*)(base + (((2 * lhi)     ^ (row & 7)) << 4));
      intx4 hi = *(const intx4*)(base + (((2 * lhi + 1) ^ (row & 7)) << 4));
      bfrag[c] = intx8{lo.x, lo.y, lo.z, lo.w, hi.x, hi.y, hi.z, hi.w};
    }
    floatx4 acc[4][4] = {};
    #pragma unroll
    for (int r = 0; r < 4; ++r) {
      const int row = wr * 64 + r * 16 + llo;
      const uint8_t* base = Abuf + row * DD;
      intx4 lo = *(const intx4*)(base + (((2 * lhi)     ^ (row & 7)) << 4));
      intx4 hi = *(const intx4*)(base + (((2 * lhi + 1) ^ (row & 7)) << 4));
      intx8 afrag = intx8{lo.x, lo.y, lo.z, lo.w, hi.x, hi.y, hi.z, hi.w};
      #pragma unroll
      for (int c = 0; c < 4; ++c)
        acc[r][c] = __builtin_amdgcn_mfma_scale_f32_16x16x128_f8f6f4(
            afrag, bfrag[c], acc[r][c], 0, 0, 0, 0x7F7F7F7F, 0, 0x7F7F7F7F);
    }

    // e = exp(acc) (acc is already 10*cos); diag masked (uniform branch).
    // C/D layout: col = lane&15, row = (lane>>4)*4 + reg.
    float colacc[4] = {0.f, 0.f, 0.f, 0.f};
    if (diag) {
      #pragma unroll
      for (int r = 0; r < 4; ++r) {
        #pragma unroll
        for (int c = 0; c < 4; ++c) {
          const int col = wc * 64 + c * 16 + llo;
          #pragma unroll
          for (int j = 0; j < 4; ++j) {
            const int row = wr * 64 + r * 16 + lhi * 4 + j;
            float e = __expf(acc[r][c][j]);
            if (row == col) e = 0.f;
            rowacc[r][j] += e;
            colacc[c] += e;
          }
        }
      }
    } else {
      #pragma unroll
      for (int r = 0; r < 4; ++r) {
        #pragma unroll
        for (int c = 0; c < 4; ++c) {
          #pragma unroll
          for (int j = 0; j < 4; ++j) {
            float e = __expf(acc[r][c][j]);
            rowacc[r][j] += e;
            colacc[c] += e;
          }
        }
      }
    }
    // Col partials for this tile -> comb[256*(1+s)] (diag tile's col-half
    // is never read by K3; writing it is harmless).
    #pragma unroll
    for (int c = 0; c < 4; ++c) {
      float sc = colacc[c];
      sc += __shfl_xor(sc, 16, 64);
      sc += __shfl_xor(sc, 32, 64);          // full col sum over wave's 64 rows
      if (lhi == 0) comb[256 * (1 + s) + wr * 128 + wc * 64 + c * 16 + llo] = sc;
    }
  }

  // Row partials (whole chunk) -> comb[0..256).
  #pragma unroll
  for (int r = 0; r < 4; ++r) {
    #pragma unroll
    for (int j = 0; j < 4; ++j) {
      float s = row16_sum(rowacc[r][j]);     // row sum over wave's 64 cols (x nt tiles)
      if (llo == j) comb[wc * 128 + wr * 64 + r * 16 + lhi * 4 + j] = s;
    }
  }
  __syncthreads();

  // Coalesced stores. Row-half of t0 = chunk row partials (K3 reads row
  // partials ONLY at chunk-start slots). Col-halves per tile.
  if (tid < 128) {
    scratch[(size_t)t0 * 256 + tid] = comb[tid] + comb[128 + tid];
  } else {
    const int i = tid - 128;
    scratch[(size_t)t0 * 256 + 128 + i] = comb[256 + i] + comb[256 + 128 + i];
    if (nt == 2)
      scratch[(size_t)(t0 + 1) * 256 + 128 + i] = comb[512 + i] + comb[512 + 128 + i];
  }
}

// K3: gather-reduce + fused tail. One block per 128-row panel P (64 blocks).
// R8: 512 threads, k-split x4 (R7's latency medicine applied again): row
// z = P*128+idx sums M = ceil((64-P)/2) + P partials, ~12 serial loads per
// thread. Slots:
//   chunk row-halves of row P:  FCUM(P)+2m, m=0..ceil((64-P)/2)-1
//   col-halves (bi,P), bi<P:    FCUM(bi)+(P-bi)
// Then log, block-reduce, 2 atomicAdds; last block (relaxed counter, no
// fences — 64 blocks, negligible) emits the final scalar.
__global__ __launch_bounds__(512) void mp_reduce(const float* __restrict__ scratch,
                                                 const float* __restrict__ pos,
                                                 float* __restrict__ accs,
                                                 uint32_t* __restrict__ cnt,
                                                 float* __restrict__ out) {
  const int P = blockIdx.x;
  const int tid = threadIdx.x;
  const int idx = tid & 127, h = tid >> 7;       // h in {0,1,2,3}
  const int nr2 = (NPAN - P + 1) >> 1;           // chunks in triangle row P
  const int M = nr2 + P;                         // partials feeding this panel
  const int base = FCUM(P);

  float s = 0.f;
  #pragma unroll 4
  for (int k = h; k < M; k += 4) {
    int off;
    if (k < nr2) {
      off = (base + 2 * k) * 256 + idx;                    // row-half, chunk m=k
    } else {
      const int b2 = k - nr2;                              // bi in [0,P)
      off = (FCUM(b2) + (P - b2)) * 256 + 128 + idx;       // col-half (b2,P)
    }
    s += scratch[off];
  }
  __shared__ float part[512];
  part[tid] = s;
  __syncthreads();

  float l = 0.f, pp = 0.f;
  if (tid < 128) {
    l = logf(part[idx] + part[128 + idx] + part[256 + idx] + part[384 + idx]);
    pp = (P < 48) ? pos[P * 128 + idx] : 0.f;    // panels 0..47 are x-rows
  }
  #pragma unroll
  for (int m = 1; m < 64; m <<= 1) {
    l += __shfl_xor(l, m, 64);
    pp += __shfl_xor(pp, m, 64);
  }
  __shared__ float rl2[8], rp2[8];
  __shared__ int lastflag;
  if ((tid & 63) == 0) { rl2[tid >> 6] = l; rp2[tid >> 6] = pp; }
  __syncthreads();
  if (tid == 0) {
    float SL = 0.f, SP = 0.f;
    #pragma unroll
    for (int w = 0; w < 8; ++w) { SL += rl2[w]; SP += rp2[w]; }
    atomicAdd(&accs[0], SL);
    atomicAdd(&accs[1], SP);
  }
  asm volatile("s_waitcnt vmcnt(0)" ::: "memory");  // this wave's atomics acked
  __syncthreads();
  if (tid == 0) {
    uint32_t old = __hip_atomic_fetch_add(cnt, 1u, __ATOMIC_RELAXED,
                                          __HIP_MEMORY_SCOPE_AGENT);
    lastflag = (old == NPAN - 1);
  }
  __syncthreads();
  if (lastflag && tid == 0) {
    float S  = __hip_atomic_load(&accs[0], __ATOMIC_RELAXED, __HIP_MEMORY_SCOPE_AGENT);
    float Pp = __hip_atomic_load(&accs[1], __ATOMIC_RELAXED, __HIP_MEMORY_SCOPE_AGENT);
    const float loss_neg = S / (float)NTOT + LOG_SUB_FRAC;
    const float loss_pos = Pp * (10.0f / (float)NX);  // WEIGHT*(1/TEMP)/(B*NPOS)
    out[0] = loss_neg - loss_pos;
  }
}

extern "C" void kernel_launch(void* const* d_in, const int* in_sizes, int n_in,
                              void* d_out, int out_size, void* d_ws, size_t ws_size,
                              hipStream_t stream) {
  const float* x  = (const float*)d_in[0];   // [6144, 128] f32
  const float* xp = (const float*)d_in[1];   // [2048, 128] f32
  float* out = (float*)d_out;                // scalar f32

  char* ws = (char*)d_ws;
  uint8_t* znb8  = (uint8_t*)ws;                                   // 1 MB
  float* pos     = (float*)(ws + (1u << 20));                      // 24 KB (pad 32K)
  float* scratch = (float*)(ws + (1u << 20) + (32u << 10));        // 2080*1KB
  float* accs    = (float*)(ws + (1u << 20) + (32u << 10) + NBLK * 1024u);
  uint32_t* cnt  = (uint32_t*)(ws + (1u << 20) + (32u << 10) + NBLK * 1024u + 8u);

  mp_norm<<<NTOT / 8, 256, 0, stream>>>(x, xp, znb8, pos, accs, cnt);
  mp_simexp<<<NCHK, 256, 0, stream>>>(znb8, scratch);
  mp_reduce<<<NPAN, 512, 0, stream>>>(scratch, pos, accs, cnt, out);
}